// Round 8
// baseline (83.188 us; speedup 1.0000x reference)
//
#include <hip/hip_runtime.h>
#include <math.h>

#define BB 8
#define NN 512
#define FF 32
#define HH 64
#define NEG_BIG (-1.0e30f)

__device__ __forceinline__ float lane_bcast(float v, int l) {
    return __int_as_float(__builtin_amdgcn_readlane(__float_as_int(v), l));
}

// ---------------------------------------------------------------------------
// encode: h = relu(x@W_enc+b); zi = h@W_e1[:H]+b_e1 (folded); zj = h@W_e1[H:]
// grid 1024 x 256: block = 4 rows, wave qu owns row, lane hh owns column.
// x row loaded per-lane once, broadcast via v_readlane -> NO scalar loads
// mixed into the load stream (s_load + vload mixing forces lgkmcnt(0)
// drains; that was R7's hidden stall).
// ---------------------------------------------------------------------------
__global__ __launch_bounds__(256) void encode_kernel(
    const float* __restrict__ x, const float* __restrict__ W_enc,
    const float* __restrict__ b_enc, const float* __restrict__ W_e1,
    const float* __restrict__ b_e1,
    float* __restrict__ h, float* __restrict__ zi, float* __restrict__ zj)
{
    const int t = threadIdx.x;
    const int hh = t & 63;
    const int qu = __builtin_amdgcn_readfirstlane(t >> 6);
    const int gR = blockIdx.x * 4 + qu;           // 0..B*N-1

    const float xv = x[gR * FF + (hh & 31)];      // coalesced; lanes 32+ dup
    float acc = b_enc[hh];
#pragma unroll 8
    for (int k = 0; k < FF; ++k)
        acc = fmaf(lane_bcast(xv, k), W_enc[k * HH + hh], acc);
    const float hval = fmaxf(acc, 0.f);
    h[gR * HH + hh] = hval;

    float z1 = b_e1[hh], z2 = 0.f;
#pragma unroll 8
    for (int k = 0; k < HH; ++k) {
        const float hk = lane_bcast(hval, k);
        z1 = fmaf(hk, W_e1[k * HH + hh], z1);
        z2 = fmaf(hk, W_e1[(HH + k) * HH + hh], z2);
    }
    zi[gR * HH + hh] = z1;
    zj[gR * HH + hh] = z2;
}

// ---------------------------------------------------------------------------
// adj: logits[i,j] = sum_k relu(zi[i,k]+zj[j,k])*W_e2[k]+b_e2, diag -inf,
// softmax over j.  grid 1024 x 256: block = (b, 4 rows); wave qu owns
// j-quarter, lane tj handles j0=128qu+tj, j1=j0+64 for all 4 rows.
// zi rows + W_e2 live in REGISTERS (v_readlane broadcast) -> hot loop is
// pure {2 ds_read + VALU}, in-order, no s_load drains.
// zjs[512][17]: stride 17 -> conflict-free.
// ---------------------------------------------------------------------------
__global__ __launch_bounds__(256) void adj_kernel(
    const float* __restrict__ zi, const float* __restrict__ zj,
    const float* __restrict__ W_e2, const float* __restrict__ b_e2,
    float* __restrict__ adj)
{
    const int b = blockIdx.x >> 7;
    const int i0 = (blockIdx.x & 127) << 2;
    const int t = threadIdx.x;
    const int qu = __builtin_amdgcn_readfirstlane(t >> 6);
    const int tj = t & 63;
    const int j0 = (qu << 7) + tj;
    const int j1 = j0 + 64;

    __shared__ float zjs[NN][17];
    __shared__ float red[4][8];

    // per-lane register copies: zr[r] holds zi[i0+r][tj], wv holds W_e2[tj]
    float zr[4];
#pragma unroll
    for (int r = 0; r < 4; ++r) zr[r] = zi[(b * NN + i0 + r) * HH + tj];
    const float wv = W_e2[tj];

    const float be2 = b_e2[0];
    float acc0[4], acc1[4];
#pragma unroll
    for (int r = 0; r < 4; ++r) { acc0[r] = be2; acc1[r] = be2; }

    for (int kp = 0; kp < 4; ++kp) {
        __syncthreads();
        {   // stage zj[:, kp*16 : kp*16+16] as float4
            const int idx4 = t;                    // 2048 float4 / 256 thr = 8
#pragma unroll
            for (int u = 0; u < 8; ++u) {
                const int i4 = idx4 + u * 256;
                const int row = i4 >> 2, c4 = i4 & 3;
                *(float4*)&zjs[row][c4 * 4] =
                    ((const float4*)(zj + (size_t)(b * NN + row) * HH))[kp * 4 + c4];
            }
        }
        __syncthreads();
#pragma unroll
        for (int c = 0; c < 16; ++c) {
            const int k = (kp << 4) + c;
            const float w = lane_bcast(wv, k);
            const float zj0 = zjs[j0][c];
            const float zj1 = zjs[j1][c];
#pragma unroll
            for (int r = 0; r < 4; ++r) {
                const float zv = lane_bcast(zr[r], k);
                acc0[r] = fmaf(fmaxf(zv + zj0, 0.f), w, acc0[r]);
                acc1[r] = fmaf(fmaxf(zv + zj1, 0.f), w, acc1[r]);
            }
        }
    }

#pragma unroll
    for (int r = 0; r < 4; ++r) {
        const int irow = i0 + r;
        if (j0 == irow) acc0[r] = NEG_BIG;
        if (j1 == irow) acc1[r] = NEG_BIG;
    }

    float wmax[4];
#pragma unroll
    for (int r = 0; r < 4; ++r) {
        float m = fmaxf(acc0[r], acc1[r]);
#pragma unroll
        for (int off = 32; off >= 1; off >>= 1) m = fmaxf(m, __shfl_xor(m, off));
        wmax[r] = m;
    }
    if (tj == 0) {
#pragma unroll
        for (int r = 0; r < 4; ++r) red[qu][r] = wmax[r];
    }
    __syncthreads();
    float M[4];
#pragma unroll
    for (int r = 0; r < 4; ++r)
        M[r] = fmaxf(fmaxf(red[0][r], red[1][r]), fmaxf(red[2][r], red[3][r]));
    __syncthreads();   // WAR on red

    float e0[4], e1[4];
#pragma unroll
    for (int r = 0; r < 4; ++r) {
        e0[r] = __expf(acc0[r] - M[r]);
        e1[r] = __expf(acc1[r] - M[r]);
        float s = e0[r] + e1[r];
#pragma unroll
        for (int off = 32; off >= 1; off >>= 1) s += __shfl_xor(s, off);
        if (tj == 0) red[qu][r] = s;
    }
    __syncthreads();
#pragma unroll
    for (int r = 0; r < 4; ++r) {
        const float inv = 1.0f / (red[0][r] + red[1][r] + red[2][r] + red[3][r]);
        float* arow = adj + ((size_t)(b * NN + i0 + r)) * NN;
        arow[j0] = e0[r] * inv;
        arow[j1] = e1[r] * inv;
    }
}

// ---------------------------------------------------------------------------
// layer (msg + GRU fused).  grid 256 x 1024: block = (b, 16 rows), 1/CU.
// adj tile (16x512 = 32 KB, contiguous in global) staged to LDS via flat
// float4 copy; phase A reads it as broadcast ds_read_b128 (in-order,
// deeply pipelined) -> NO s_loads anywhere in hot loops.
//  A: wave=(rg,kc): rows rg*8..+8 x j-chunk [64kc,64kc+64); partials->U.red
//  B: wave w owns row w: m reduce + mm = relu(m@Wmsg+b)
//  C: wave=(half,rp): gi (from mm) / gh (from hown) for rows 2rp,2rp+1
//  finalize: wave w row w: GRU; optional 16-row partial sum for readout.
// ---------------------------------------------------------------------------
__global__ __launch_bounds__(1024, 4) void layer_kernel(
    const float* __restrict__ adjw, const float* __restrict__ h_in,
    const float* __restrict__ Wmsg, const float* __restrict__ bmsg,
    const float* __restrict__ Wih, const float* __restrict__ bih,
    const float* __restrict__ Whh, const float* __restrict__ bhh,
    float* __restrict__ h_out, float* __restrict__ partial)
{
    const int b  = blockIdx.x >> 5;
    const int i0 = (blockIdx.x & 31) << 4;
    const int t  = threadIdx.x;
    const int hh = t & 63;
    const int w  = __builtin_amdgcn_readfirstlane(t >> 6);   // 0..15
    const int gR0 = b * NN + i0;

    __shared__ float adjs[16][512];      // 32 KB
    __shared__ union {
        float red[8][16][66];            // phase A partials  [kc][row][hh]
        float gbuf[2][16][3][66];        // phase C gates
    } U;
    __shared__ float mfull[16][66];
    __shared__ float mmfull[16][66];
    __shared__ float hown[16][66];

    // stage adj tile (contiguous 32 KB) + own h rows
    {
        const float4* asrc = (const float4*)(adjw + (size_t)gR0 * NN);
        float4* adst = (float4*)&adjs[0][0];
        adst[t] = asrc[t];
        adst[t + 1024] = asrc[t + 1024];
    }
    hown[w][hh] = h_in[(size_t)(gR0 + w) * HH + hh];
    __syncthreads();

    //=== phase A: m = adj @ h =============================================
    const int rg = w >> 3, kc = w & 7;
    const float* hj = h_in + (size_t)b * NN * HH + (size_t)(kc * 64) * HH + hh;

    float mac[8] = {0.f, 0.f, 0.f, 0.f, 0.f, 0.f, 0.f, 0.f};
#pragma unroll 2
    for (int j = 0; j < 64; j += 4) {
        const float h0 = hj[(j + 0) * HH];
        const float h1 = hj[(j + 1) * HH];
        const float h2 = hj[(j + 2) * HH];
        const float h3 = hj[(j + 3) * HH];
#pragma unroll
        for (int r = 0; r < 8; ++r) {
            const float4 av = *(const float4*)&adjs[rg * 8 + r][kc * 64 + j];
            mac[r] = fmaf(av.w, h3,
                     fmaf(av.z, h2,
                     fmaf(av.y, h1,
                     fmaf(av.x, h0, mac[r]))));
        }
    }
#pragma unroll
    for (int r = 0; r < 8; ++r) U.red[kc][rg * 8 + r][hh] = mac[r];
    __syncthreads();

    //=== A-reduce + phase B (wave w owns row w) ===========================
    {
        float s = 0.f;
#pragma unroll
        for (int p = 0; p < 8; ++p) s += U.red[p][w][hh];
        mfull[w][hh] = s;

        float acc = bmsg[hh];
#pragma unroll 8
        for (int k = 0; k < HH; ++k)
            acc = fmaf(mfull[w][k], Wmsg[k * HH + hh], acc);
        mmfull[w][hh] = fmaxf(acc, 0.f);
    }
    __syncthreads();

    //=== phase C: 6 gate GEMMs, wave = (half, row-pair) ===================
    const int half = w >> 3, rp = w & 7;
    {
        const float* Wg = half ? Whh : Wih;
        const float* bg = half ? bhh : bih;
        const float (*src)[66] = half ? (const float (*)[66])hown
                                      : (const float (*)[66])mmfull;
        float a0 = bg[hh], a1 = bg[64 + hh], a2 = bg[128 + hh];
        float c0 = a0, c1 = a1, c2 = a2;
#pragma unroll 2
        for (int k = 0; k < HH; ++k) {
            const float* wk = Wg + k * 192;
            const float w0 = wk[hh], w1 = wk[64 + hh], w2 = wk[128 + hh];
            const float va = src[2 * rp][k];
            const float vb = src[2 * rp + 1][k];
            a0 = fmaf(va, w0, a0); a1 = fmaf(va, w1, a1); a2 = fmaf(va, w2, a2);
            c0 = fmaf(vb, w0, c0); c1 = fmaf(vb, w1, c1); c2 = fmaf(vb, w2, c2);
        }
        U.gbuf[half][2 * rp][0][hh] = a0;
        U.gbuf[half][2 * rp][1][hh] = a1;
        U.gbuf[half][2 * rp][2][hh] = a2;
        U.gbuf[half][2 * rp + 1][0][hh] = c0;
        U.gbuf[half][2 * rp + 1][1][hh] = c1;
        U.gbuf[half][2 * rp + 1][2][hh] = c2;
    }
    __syncthreads();

    //=== finalize: wave w row w ==========================================
    {
        const float ir = U.gbuf[0][w][0][hh], iz = U.gbuf[0][w][1][hh],
                    in = U.gbuf[0][w][2][hh];
        const float hr = U.gbuf[1][w][0][hh], hz = U.gbuf[1][w][1][hh],
                    hn = U.gbuf[1][w][2][hh];
        const float rr = 1.f / (1.f + __expf(-(ir + hr)));
        const float zz = 1.f / (1.f + __expf(-(iz + hz)));
        const float nnv = tanhf(in + rr * hn);
        const float hnew = (1.f - zz) * nnv + zz * hown[w][hh];
        h_out[(size_t)(gR0 + w) * HH + hh] = hnew;

        if (partial != nullptr) {       // layer 2: per-block 16-row sum
            mfull[w][hh] = hnew;        // mfull dead after phase B
            __syncthreads();
            if (w == 0) {
                float s = 0.f;
#pragma unroll
                for (int r = 0; r < 16; ++r) s += mfull[r][hh];
                partial[blockIdx.x * 64 + hh] = s;
            }
        }
    }
}

// ---------------------------------------------------------------------------
// readout: out[b] = (sum of partials)/N @ W_out + b_out.  8 blocks x 64 thr.
// ---------------------------------------------------------------------------
__global__ __launch_bounds__(64) void readout_kernel(
    const float* __restrict__ partial, const float* __restrict__ W_out,
    const float* __restrict__ b_out, float* __restrict__ out)
{
    const int b = blockIdx.x;
    const int hh = threadIdx.x;
    float s = 0.f;
#pragma unroll 8
    for (int c = 0; c < 32; ++c)
        s += partial[(b * 32 + c) * 64 + hh];
    float v = s * (1.0f / NN) * W_out[hh];
#pragma unroll
    for (int off = 32; off >= 1; off >>= 1) v += __shfl_xor(v, off);
    if (hh == 0) out[b] = v + b_out[0];
}

extern "C" void kernel_launch(void* const* d_in, const int* in_sizes, int n_in,
                              void* d_out, int out_size, void* d_ws, size_t ws_size,
                              hipStream_t stream)
{
    const float* x     = (const float*)d_in[0];
    const float* W_enc = (const float*)d_in[1];
    const float* b_enc = (const float*)d_in[2];
    const float* W_e1  = (const float*)d_in[3];
    const float* b_e1  = (const float*)d_in[4];
    const float* W_e2  = (const float*)d_in[5];
    const float* b_e2  = (const float*)d_in[6];
    const float* W_msg = (const float*)d_in[7];
    const float* b_msg = (const float*)d_in[8];
    const float* W_ih  = (const float*)d_in[9];
    const float* b_ih  = (const float*)d_in[10];
    const float* W_hh  = (const float*)d_in[11];
    const float* b_hh  = (const float*)d_in[12];
    const float* W_out = (const float*)d_in[13];
    const float* b_out = (const float*)d_in[14];
    float* out = (float*)d_out;

    float* ws  = (float*)d_ws;
    float* h0  = ws;
    float* h1  = h0 + BB * NN * HH;
    float* zi  = h1 + BB * NN * HH;
    float* zj  = zi + BB * NN * HH;
    float* prt = zj + BB * NN * HH;         // 256*64 partials
    float* adjw = prt + 256 * 64;

    encode_kernel<<<BB * NN / 4, 256, 0, stream>>>(x, W_enc, b_enc, W_e1, b_e1, h0, zi, zj);
    adj_kernel<<<BB * (NN / 4), 256, 0, stream>>>(zi, zj, W_e2, b_e2, adjw);

    layer_kernel<<<BB * (NN / 16), 1024, 0, stream>>>(
        adjw, h0, W_msg, b_msg, W_ih, b_ih, W_hh, b_hh, h1, nullptr);
    layer_kernel<<<BB * (NN / 16), 1024, 0, stream>>>(
        adjw, h1, W_msg + HH * HH, b_msg + HH,
        W_ih + HH * 3 * HH, b_ih + 3 * HH, W_hh + HH * 3 * HH, b_hh + 3 * HH,
        h0, prt);

    readout_kernel<<<BB, 64, 0, stream>>>(prt, W_out, b_out, out);
}

// Round 9
// 79.021 us; speedup vs baseline: 1.0527x; 1.0527x over previous
//
#include <hip/hip_runtime.h>
#include <math.h>

#define BB 8
#define NN 512
#define FF 32
#define HH 64
#define NEG_BIG (-1.0e30f)

__device__ __forceinline__ float lane_bcast(float v, int l) {
    return __int_as_float(__builtin_amdgcn_readlane(__float_as_int(v), l));
}

// ---------------------------------------------------------------------------
// encode: h = relu(x@W_enc+b); zi = h@W_e1[:H]+b_e1 (folded); zj = h@W_e1[H:]
// grid 1024 x 256: block = 4 rows, wave qu owns row, lane hh owns column.
// ---------------------------------------------------------------------------
__global__ __launch_bounds__(256) void encode_kernel(
    const float* __restrict__ x, const float* __restrict__ W_enc,
    const float* __restrict__ b_enc, const float* __restrict__ W_e1,
    const float* __restrict__ b_e1,
    float* __restrict__ h, float* __restrict__ zi, float* __restrict__ zj)
{
    const int t = threadIdx.x;
    const int hh = t & 63;
    const int qu = __builtin_amdgcn_readfirstlane(t >> 6);
    const int gR = blockIdx.x * 4 + qu;           // 0..B*N-1

    const float xv = x[gR * FF + (hh & 31)];      // coalesced; lanes 32+ dup
    float acc = b_enc[hh];
#pragma unroll 8
    for (int k = 0; k < FF; ++k)
        acc = fmaf(lane_bcast(xv, k), W_enc[k * HH + hh], acc);
    const float hval = fmaxf(acc, 0.f);
    h[gR * HH + hh] = hval;

    float z1 = b_e1[hh], z2 = 0.f;
#pragma unroll 8
    for (int k = 0; k < HH; ++k) {
        const float hk = lane_bcast(hval, k);
        z1 = fmaf(hk, W_e1[k * HH + hh], z1);
        z2 = fmaf(hk, W_e1[(HH + k) * HH + hh], z2);
    }
    zi[gR * HH + hh] = z1;
    zj[gR * HH + hh] = z2;
}

// ---------------------------------------------------------------------------
// adj: logits[i,j] = sum_k relu(zi[i,k]+zj[j,k])*W_e2[k]+b_e2, diag -inf,
// softmax over j.  grid 1024 x 256: block = (b, 4 rows); wave qu owns
// j-quarter, lane tj handles j0=128qu+tj, j1=j0+64 for all 4 rows.
// zi rows + W_e2 in registers (v_readlane broadcast); zjs[512][17].
// ---------------------------------------------------------------------------
__global__ __launch_bounds__(256) void adj_kernel(
    const float* __restrict__ zi, const float* __restrict__ zj,
    const float* __restrict__ W_e2, const float* __restrict__ b_e2,
    float* __restrict__ adj)
{
    const int b = blockIdx.x >> 7;
    const int i0 = (blockIdx.x & 127) << 2;
    const int t = threadIdx.x;
    const int qu = __builtin_amdgcn_readfirstlane(t >> 6);
    const int tj = t & 63;
    const int j0 = (qu << 7) + tj;
    const int j1 = j0 + 64;

    __shared__ float zjs[NN][17];
    __shared__ float red[4][8];

    float zr[4];
#pragma unroll
    for (int r = 0; r < 4; ++r) zr[r] = zi[(b * NN + i0 + r) * HH + tj];
    const float wv = W_e2[tj];

    const float be2 = b_e2[0];
    float acc0[4], acc1[4];
#pragma unroll
    for (int r = 0; r < 4; ++r) { acc0[r] = be2; acc1[r] = be2; }

    for (int kp = 0; kp < 4; ++kp) {
        __syncthreads();
        {
            const int idx4 = t;
#pragma unroll
            for (int u = 0; u < 8; ++u) {
                const int i4 = idx4 + u * 256;
                const int row = i4 >> 2, c4 = i4 & 3;
                *(float4*)&zjs[row][c4 * 4] =
                    ((const float4*)(zj + (size_t)(b * NN + row) * HH))[kp * 4 + c4];
            }
        }
        __syncthreads();
#pragma unroll
        for (int c = 0; c < 16; ++c) {
            const int k = (kp << 4) + c;
            const float w = lane_bcast(wv, k);
            const float zj0 = zjs[j0][c];
            const float zj1 = zjs[j1][c];
#pragma unroll
            for (int r = 0; r < 4; ++r) {
                const float zv = lane_bcast(zr[r], k);
                acc0[r] = fmaf(fmaxf(zv + zj0, 0.f), w, acc0[r]);
                acc1[r] = fmaf(fmaxf(zv + zj1, 0.f), w, acc1[r]);
            }
        }
    }

#pragma unroll
    for (int r = 0; r < 4; ++r) {
        const int irow = i0 + r;
        if (j0 == irow) acc0[r] = NEG_BIG;
        if (j1 == irow) acc1[r] = NEG_BIG;
    }

    float wmax[4];
#pragma unroll
    for (int r = 0; r < 4; ++r) {
        float m = fmaxf(acc0[r], acc1[r]);
#pragma unroll
        for (int off = 32; off >= 1; off >>= 1) m = fmaxf(m, __shfl_xor(m, off));
        wmax[r] = m;
    }
    if (tj == 0) {
#pragma unroll
        for (int r = 0; r < 4; ++r) red[qu][r] = wmax[r];
    }
    __syncthreads();
    float M[4];
#pragma unroll
    for (int r = 0; r < 4; ++r)
        M[r] = fmaxf(fmaxf(red[0][r], red[1][r]), fmaxf(red[2][r], red[3][r]));
    __syncthreads();

    float e0[4], e1[4];
#pragma unroll
    for (int r = 0; r < 4; ++r) {
        e0[r] = __expf(acc0[r] - M[r]);
        e1[r] = __expf(acc1[r] - M[r]);
        float s = e0[r] + e1[r];
#pragma unroll
        for (int off = 32; off >= 1; off >>= 1) s += __shfl_xor(s, off);
        if (tj == 0) red[qu][r] = s;
    }
    __syncthreads();
#pragma unroll
    for (int r = 0; r < 4; ++r) {
        const float inv = 1.0f / (red[0][r] + red[1][r] + red[2][r] + red[3][r]);
        float* arow = adj + ((size_t)(b * NN + i0 + r)) * NN;
        arow[j0] = e0[r] * inv;
        arow[j1] = e1[r] * inv;
    }
}

// ---------------------------------------------------------------------------
// layer (msg + GRU fused).  grid 512 x 512 (8 waves, 2 blocks/CU = 16 w/CU):
// block = (b, 8 rows).
//  A: wave w = j-chunk [64w,64w+64), all 8 rows in regs (adj tile from LDS
//     as wave-uniform b128 broadcasts); partials -> U.red.
//  B: wave w = row w: reduce partials, mm = relu(m@Wmsg+b) via readlane.
//  C: wave = (half, kh, rq): 3 gates x 4 rows x 32 k -> only 96 loads +
//     384 FMA per wave (serial chain 1/4 of R8); partials -> U.gbuf.
//  finalize: wave w = row w: sum k-halves, GRU, store (+readout partial).
// ---------------------------------------------------------------------------
__global__ __launch_bounds__(512, 4) void layer_kernel(
    const float* __restrict__ adjw, const float* __restrict__ h_in,
    const float* __restrict__ Wmsg, const float* __restrict__ bmsg,
    const float* __restrict__ Wih, const float* __restrict__ bih,
    const float* __restrict__ Whh, const float* __restrict__ bhh,
    float* __restrict__ h_out, float* __restrict__ partial)
{
    const int b  = blockIdx.x >> 6;               // 512 blocks = 8 b x 64 tiles
    const int i0 = (blockIdx.x & 63) << 3;        // 8 rows
    const int t  = threadIdx.x;                   // 0..511
    const int hh = t & 63;
    const int w  = __builtin_amdgcn_readfirstlane(t >> 6);   // 0..7
    const int gR0 = b * NN + i0;

    __shared__ float adjs[8][512];                // 16 KB, read-only after stage
    __shared__ union {
        float red[8][8][66];                      // A partials [kc][row][hh]
        float gbuf[2][2][8][3][66];               // C partials [half][kh][row][g][hh]
    } U;
    __shared__ float mml[8][66];
    __shared__ float hol[8][66];

    // stage adj tile (8x512 contiguous = 16 KB) + own h rows
    {
        const float4* asrc = (const float4*)(adjw + (size_t)gR0 * NN);
        float4* adst = (float4*)&adjs[0][0];
        adst[t] = asrc[t];
        adst[t + 512] = asrc[t + 512];
    }
    hol[t >> 6][hh] = h_in[(size_t)(gR0 + (t >> 6)) * HH + hh];
    __syncthreads();

    //=== phase A: m partials ==============================================
    {
        const float* hj = h_in + (size_t)b * NN * HH + (size_t)(w * 64) * HH + hh;
        float mac[8] = {0.f, 0.f, 0.f, 0.f, 0.f, 0.f, 0.f, 0.f};
#pragma unroll 2
        for (int j = 0; j < 64; j += 4) {
            const float h0 = hj[(j + 0) * HH];
            const float h1 = hj[(j + 1) * HH];
            const float h2 = hj[(j + 2) * HH];
            const float h3 = hj[(j + 3) * HH];
#pragma unroll
            for (int r = 0; r < 8; ++r) {
                const float4 av = *(const float4*)&adjs[r][w * 64 + j];
                mac[r] = fmaf(av.w, h3,
                         fmaf(av.z, h2,
                         fmaf(av.y, h1,
                         fmaf(av.x, h0, mac[r]))));
            }
        }
#pragma unroll
        for (int r = 0; r < 8; ++r) U.red[w][r][hh] = mac[r];
    }
    __syncthreads();

    //=== phase B: wave w = row w: m reduce + mm (readlane, no LDS trip) ===
    {
        float m = 0.f;
#pragma unroll
        for (int p = 0; p < 8; ++p) m += U.red[p][w][hh];
        float acc = bmsg[hh];
#pragma unroll 4
        for (int k = 0; k < HH; ++k)
            acc = fmaf(lane_bcast(m, k), Wmsg[k * HH + hh], acc);
        mml[w][hh] = fmaxf(acc, 0.f);
    }
    __syncthreads();

    //=== phase C: wave = (half, kh, rq), 4 rows x 3 gates x 32 k ==========
    const int half = w >> 2, kh = (w >> 1) & 1, rq = w & 1;
    {
        const float* Wg = half ? Whh : Wih;
        const float* bg = half ? bhh : bih;
        float src[4];
#pragma unroll
        for (int r = 0; r < 4; ++r)
            src[r] = half ? hol[rq * 4 + r][hh] : mml[rq * 4 + r][hh];
        float a0[4], a1[4], a2[4];
#pragma unroll
        for (int r = 0; r < 4; ++r) {
            a0[r] = kh ? 0.f : bg[hh];
            a1[r] = kh ? 0.f : bg[64 + hh];
            a2[r] = kh ? 0.f : bg[128 + hh];
        }
        const int k0 = kh * 32;
#pragma unroll 2
        for (int kk = 0; kk < 32; ++kk) {
            const float* wk = Wg + (k0 + kk) * 192;
            const float w0 = wk[hh], w1 = wk[64 + hh], w2 = wk[128 + hh];
#pragma unroll
            for (int r = 0; r < 4; ++r) {
                const float v = lane_bcast(src[r], k0 + kk);
                a0[r] = fmaf(v, w0, a0[r]);
                a1[r] = fmaf(v, w1, a1[r]);
                a2[r] = fmaf(v, w2, a2[r]);
            }
        }
#pragma unroll
        for (int r = 0; r < 4; ++r) {
            U.gbuf[half][kh][rq * 4 + r][0][hh] = a0[r];
            U.gbuf[half][kh][rq * 4 + r][1][hh] = a1[r];
            U.gbuf[half][kh][rq * 4 + r][2][hh] = a2[r];
        }
    }
    __syncthreads();

    //=== finalize: wave w = row w ========================================
    {
        const float ir = U.gbuf[0][0][w][0][hh] + U.gbuf[0][1][w][0][hh];
        const float iz = U.gbuf[0][0][w][1][hh] + U.gbuf[0][1][w][1][hh];
        const float in = U.gbuf[0][0][w][2][hh] + U.gbuf[0][1][w][2][hh];
        const float hr = U.gbuf[1][0][w][0][hh] + U.gbuf[1][1][w][0][hh];
        const float hz = U.gbuf[1][0][w][1][hh] + U.gbuf[1][1][w][1][hh];
        const float hn = U.gbuf[1][0][w][2][hh] + U.gbuf[1][1][w][2][hh];
        const float rr = 1.f / (1.f + __expf(-(ir + hr)));
        const float zz = 1.f / (1.f + __expf(-(iz + hz)));
        const float nnv = tanhf(in + rr * hn);
        const float hnew = (1.f - zz) * nnv + zz * hol[w][hh];
        h_out[(size_t)(gR0 + w) * HH + hh] = hnew;

        if (partial != nullptr) {                 // layer 2: 8-row block sum
            __syncthreads();                      // mml dead after C preload
            mml[w][hh] = hnew;
            __syncthreads();
            if (w == 0) {
                float s = 0.f;
#pragma unroll
                for (int r = 0; r < 8; ++r) s += mml[r][hh];
                partial[blockIdx.x * 64 + hh] = s;
            }
        }
    }
}

// ---------------------------------------------------------------------------
// readout: out[b] = (sum of 64 tile-partials)/N @ W_out + b_out.
// ---------------------------------------------------------------------------
__global__ __launch_bounds__(64) void readout_kernel(
    const float* __restrict__ partial, const float* __restrict__ W_out,
    const float* __restrict__ b_out, float* __restrict__ out)
{
    const int b = blockIdx.x;
    const int hh = threadIdx.x;
    float s = 0.f;
#pragma unroll 8
    for (int c = 0; c < 64; ++c)
        s += partial[(b * 64 + c) * 64 + hh];
    float v = s * (1.0f / NN) * W_out[hh];
#pragma unroll
    for (int off = 32; off >= 1; off >>= 1) v += __shfl_xor(v, off);
    if (hh == 0) out[b] = v + b_out[0];
}

extern "C" void kernel_launch(void* const* d_in, const int* in_sizes, int n_in,
                              void* d_out, int out_size, void* d_ws, size_t ws_size,
                              hipStream_t stream)
{
    const float* x     = (const float*)d_in[0];
    const float* W_enc = (const float*)d_in[1];
    const float* b_enc = (const float*)d_in[2];
    const float* W_e1  = (const float*)d_in[3];
    const float* b_e1  = (const float*)d_in[4];
    const float* W_e2  = (const float*)d_in[5];
    const float* b_e2  = (const float*)d_in[6];
    const float* W_msg = (const float*)d_in[7];
    const float* b_msg = (const float*)d_in[8];
    const float* W_ih  = (const float*)d_in[9];
    const float* b_ih  = (const float*)d_in[10];
    const float* W_hh  = (const float*)d_in[11];
    const float* b_hh  = (const float*)d_in[12];
    const float* W_out = (const float*)d_in[13];
    const float* b_out = (const float*)d_in[14];
    float* out = (float*)d_out;

    float* ws  = (float*)d_ws;
    float* h0  = ws;
    float* h1  = h0 + BB * NN * HH;
    float* zi  = h1 + BB * NN * HH;
    float* zj  = zi + BB * NN * HH;
    float* prt = zj + BB * NN * HH;         // 512*64 partials
    float* adjw = prt + 512 * 64;

    encode_kernel<<<BB * NN / 4, 256, 0, stream>>>(x, W_enc, b_enc, W_e1, b_e1, h0, zi, zj);
    adj_kernel<<<BB * (NN / 4), 256, 0, stream>>>(zi, zj, W_e2, b_e2, adjw);

    layer_kernel<<<BB * (NN / 8), 512, 0, stream>>>(
        adjw, h0, W_msg, b_msg, W_ih, b_ih, W_hh, b_hh, h1, nullptr);
    layer_kernel<<<BB * (NN / 8), 512, 0, stream>>>(
        adjw, h1, W_msg + HH * HH, b_msg + HH,
        W_ih + HH * 3 * HH, b_ih + 3 * HH, W_hh + HH * 3 * HH, b_hh + 3 * HH,
        h0, prt);

    readout_kernel<<<BB, 64, 0, stream>>>(prt, W_out, b_out, out);
}